// Round 1
// baseline (121.160 us; speedup 1.0000x reference)
//
#include <hip/hip_runtime.h>
#include <hip/hip_cooperative_groups.h>

namespace cg = cooperative_groups;

// Chamfer-style 3-level loss. P=128 polygons, N=128 pred pts, M=1024 gt pts.
// Round-4 change: FUSE the two dispatches into one cooperative kernel.
// Evidence: rocprof top-5 shows only 40us harness fills -> both our kernels
// are individually <39.7us, yet timed region is 68us. VALU floor is ~3.2us
// (252M lane-ops / 32768 lanes/cyc @2.4GHz), so the gap is dispatch/graph
// overhead + inter-kernel dependency drain, not pipe saturation.
// Phase 1 math is bit-identical to the 67.2us version (absmax must stay 0).
#define NPOLY 128
#define NPTS  128
#define NGT   1024
#define NBLK  (3 * NPOLY * 2)   // 768 blocks, 3/CU co-resident

__global__ __launch_bounds__(256) void chamfer_fused_kernel(
    const float* __restrict__ pred0,
    const float* __restrict__ pred1,
    const float* __restrict__ pred2,
    const float* __restrict__ gt,
    float* __restrict__ partial,
    float* __restrict__ out) {
    __shared__ float4 gts[NGT / 2];   // 8 KiB: this polygon's gt as point-pairs
    __shared__ float2 pxy[64];        // this block's 64 pred points
    __shared__ float wave_sums[4];

    const int b     = blockIdx.x;
    const int half  = b & 1;
    const int poly  = (b >> 1) & (NPOLY - 1);
    const int level = b >> 8;         // 256 blocks per level

    const float* pred = (level == 0) ? pred0 : ((level == 1) ? pred1 : pred2);
    const float  w    = (level == 0) ? 0.2f : ((level == 1) ? 0.3f : 0.5f);

    const int t = threadIdx.x;

    // Stage gt: 512 float4 (coalesced, 2 per thread).
    const float4* gsrc = (const float4*)(gt + (size_t)poly * (NGT * 2));
    gts[t]       = gsrc[t];
    gts[t + 256] = gsrc[t + 256];

    // Stage this block's 64 pred points: coords [1:3] of [P,N,3] layout.
    if (t < 64) {
        const float* pp = pred + ((size_t)poly * NPTS + half * 64 + t) * 3 + 1;
        pxy[t] = make_float2(pp[0], pp[1]);
    }
    __syncthreads();

    const int s = t & 31;    // gt slice
    const int g = t >> 5;    // point-group 0..7

    float px[8], py[8], dmin[8];
#pragma unroll
    for (int p = 0; p < 8; ++p) {
        float2 q = pxy[g * 8 + p];   // 32-lane broadcast, conflict-free
        px[p] = q.x;
        py[p] = q.y;
        dmin[p] = 1e30f;
    }

    // Each wave scans the full gt set: 16 ds_read_b128/thread, 16 dists each.
#pragma unroll
    for (int j = 0; j < NGT / 2 / 32; ++j) {
        float4 gq = gts[(j << 5) + s];
#pragma unroll
        for (int p = 0; p < 8; ++p) {
            float dx0 = px[p] - gq.x, dy0 = py[p] - gq.y;
            float d0  = fmaf(dx0, dx0, dy0 * dy0);
            float dx1 = px[p] - gq.z, dy1 = py[p] - gq.w;
            float d1  = fmaf(dx1, dx1, dy1 * dy1);
            dmin[p] = fminf(dmin[p], fminf(d0, d1));
        }
    }

    // Min across the 32 slices.
#pragma unroll
    for (int o = 1; o <= 16; o <<= 1) {
#pragma unroll
        for (int p = 0; p < 8; ++p)
            dmin[p] = fminf(dmin[p], __shfl_xor(dmin[p], o));
    }

    // sqrt AFTER the full min (monotone -> same selection as reference).
    float d = 0.0f;
#pragma unroll
    for (int p = 0; p < 8; ++p) d += sqrtf(dmin[p]);

    // Other point-group in this wave -> wave total (16 points).
    d += __shfl_xor(d, 32);

    if ((t & 63) == 0) wave_sums[t >> 6] = d;
    __syncthreads();

    if (t == 0) {
        float total = wave_sums[0] + wave_sums[1] + wave_sums[2] + wave_sums[3];
        partial[b] = total * (w * (1.0f / (3.0f * NPOLY * NPTS)));
    }

    // Grid-wide barrier replaces the second dispatch. grid.sync() provides
    // device-scope release/acquire, so block 0 sees all 768 partials.
    cg::this_grid().sync();

    if (b == 0) {
        float s2 = partial[t] + partial[t + 256] + partial[t + 512];
#pragma unroll
        for (int o = 1; o <= 32; o <<= 1) s2 += __shfl_xor(s2, o);
        if ((t & 63) == 0) wave_sums[t >> 6] = s2;
        __syncthreads();
        if (t == 0)
            out[0] = wave_sums[0] + wave_sums[1] + wave_sums[2] + wave_sums[3];
    }
}

extern "C" void kernel_launch(void* const* d_in, const int* in_sizes, int n_in,
                              void* d_out, int out_size, void* d_ws, size_t ws_size,
                              hipStream_t stream) {
    const float* pred0 = (const float*)d_in[0];
    const float* pred1 = (const float*)d_in[1];
    const float* pred2 = (const float*)d_in[2];
    const float* gt    = (const float*)d_in[3];
    float* partial = (float*)d_ws;
    float* out     = (float*)d_out;

    void* args[] = {&pred0, &pred1, &pred2, &gt, &partial, &out};
    hipLaunchCooperativeKernel((void*)chamfer_fused_kernel, dim3(NBLK), dim3(256),
                               args, 0, stream);
}

// Round 2
// 67.966 us; speedup vs baseline: 1.7827x; 1.7827x over previous
//
#include <hip/hip_runtime.h>

// Chamfer-style 3-level loss. P=128 polygons, N=128 pred pts, M=1024 gt pts.
// Round-5 change: (a) revert cooperative launch (R4: +75us host overhead,
// 121us wall vs 45us device); (b) remove ALL LDS staging from phase 1.
// Evidence: R4 rocprof showed phase VGPR_Count=24 -- impossible to hold
// px[8]+py[8]+dmin[8] (24 regs) + gq + addresses, and no scratch traffic in
// FETCH/WRITE: compiler demoted px/py to per-use LDS re-reads, turning the
// inner loop into a dependent ds_read chain at 3 waves/SIMD (VALUBusy 14%,
// 86% stall). gt is 1 MB (L2-resident) and pred reads are 32-lane broadcasts:
// LDS staging buys nothing (guide Common-mistake #7). Now: 16 independent
// global_load_dwordx4 prefetched into registers, broadcast pred loads, no
// barriers until the tiny end-of-block wave_sums combine (kept bit-identical
// to preserve the exact reduction tree -> absmax 0).
#define NPOLY 128
#define NPTS  128
#define NGT   1024
#define NBLK  (3 * NPOLY * 2)   // 768 partials

__global__ __launch_bounds__(256) void chamfer_partial_kernel(
    const float* __restrict__ pred0,
    const float* __restrict__ pred1,
    const float* __restrict__ pred2,
    const float* __restrict__ gt,
    float* __restrict__ partial) {
    __shared__ float wave_sums[4];

    const int b     = blockIdx.x;
    const int half  = b & 1;
    const int poly  = (b >> 1) & (NPOLY - 1);
    const int level = b >> 8;         // 256 blocks per level

    const float* pred = (level == 0) ? pred0 : ((level == 1) ? pred1 : pred2);
    const float  w    = (level == 0) ? 0.2f : ((level == 1) ? 0.3f : 0.5f);

    const int t = threadIdx.x;
    const int s = t & 31;    // gt slice
    const int g = t >> 5;    // point-group 0..7

    // gt point-pairs straight from global. Same index order as the staged
    // version: slice s scans pairs (j*32 + s). 1 MB total -> L2/L3 resident.
    const float4* gsrc = (const float4*)(gt + (size_t)poly * (NGT * 2));

    // Issue all 16 gt loads up front: independent global_load_dwordx4,
    // one latency for the whole set instead of a dependent chain.
    float4 gq[16];
#pragma unroll
    for (int j = 0; j < 16; ++j) gq[j] = gsrc[(j << 5) + s];

    // This group's 8 pred points: coords [1:3] of [P,N,3]. All 32 lanes of
    // the half-wave read the same addresses -> broadcast, L1-served.
    float px[8], py[8], dmin[8];
#pragma unroll
    for (int p = 0; p < 8; ++p) {
        const float* pp =
            pred + ((size_t)poly * NPTS + half * 64 + g * 8 + p) * 3 + 1;
        px[p]   = pp[0];
        py[p]   = pp[1];
        dmin[p] = 1e30f;
    }

    // 16 pairs x 8 points per iteration; identical FP ops and min order to
    // the previous (absmax==0) version.
#pragma unroll
    for (int j = 0; j < 16; ++j) {
        float4 gq_j = gq[j];
#pragma unroll
        for (int p = 0; p < 8; ++p) {
            float dx0 = px[p] - gq_j.x, dy0 = py[p] - gq_j.y;
            float d0  = fmaf(dx0, dx0, dy0 * dy0);
            float dx1 = px[p] - gq_j.z, dy1 = py[p] - gq_j.w;
            float d1  = fmaf(dx1, dx1, dy1 * dy1);
            dmin[p] = fminf(dmin[p], fminf(d0, d1));
        }
    }

    // Min across the 32 slices (same butterfly as before).
#pragma unroll
    for (int o = 1; o <= 16; o <<= 1) {
#pragma unroll
        for (int p = 0; p < 8; ++p)
            dmin[p] = fminf(dmin[p], __shfl_xor(dmin[p], o));
    }

    // sqrt AFTER the full min (monotone -> same selection as reference).
    float d = 0.0f;
#pragma unroll
    for (int p = 0; p < 8; ++p) d += sqrtf(dmin[p]);

    // Other point-group in this wave -> wave total (16 points).
    d += __shfl_xor(d, 32);

    if ((t & 63) == 0) wave_sums[t >> 6] = d;
    __syncthreads();

    if (t == 0) {
        float total = wave_sums[0] + wave_sums[1] + wave_sums[2] + wave_sums[3];
        partial[b] = total * (w * (1.0f / (3.0f * NPOLY * NPTS)));
    }
}

// Single block: sum 768 partials (L2-resident), plain store of the scalar.
__global__ __launch_bounds__(256) void reduce_partials_kernel(
    const float* __restrict__ partial, float* __restrict__ out) {
    __shared__ float wave_sums[4];
    const int t = threadIdx.x;
    float s = partial[t] + partial[t + 256] + partial[t + 512];
#pragma unroll
    for (int o = 1; o <= 32; o <<= 1) s += __shfl_xor(s, o);
    if ((t & 63) == 0) wave_sums[t >> 6] = s;
    __syncthreads();
    if (t == 0)
        out[0] = wave_sums[0] + wave_sums[1] + wave_sums[2] + wave_sums[3];
}

extern "C" void kernel_launch(void* const* d_in, const int* in_sizes, int n_in,
                              void* d_out, int out_size, void* d_ws, size_t ws_size,
                              hipStream_t stream) {
    const float* pred0 = (const float*)d_in[0];
    const float* pred1 = (const float*)d_in[1];
    const float* pred2 = (const float*)d_in[2];
    const float* gt    = (const float*)d_in[3];
    float* partial = (float*)d_ws;
    float* out     = (float*)d_out;

    chamfer_partial_kernel<<<NBLK, 256, 0, stream>>>(pred0, pred1, pred2, gt, partial);
    reduce_partials_kernel<<<1, 256, 0, stream>>>(partial, out);
}